// Round 4
// baseline (444.877 us; speedup 1.0000x reference)
//
#include <hip/hip_runtime.h>
#include <math.h>

// Actor_att1 on gfx950 — R4: 1-wave blocks, 64 rows/wave, fused branch loop.
// Fragment conventions HW-validated (R2/R3 pass, absmax 1.95e-3):
//   A-frag: A[m=lane&15][k=4*(lane>>4)+j] ; D/B duality lets layer outputs
//   chain as next-layer B operands in registers.
// Weight/bias fragments converted once per wave, reused over 4 row-groups.
// Both entity branches interleaved in one loop -> 8 independent MFMA chains.

#define OBS 127
#define XSS 132   // f16 LDS row stride (row r starts at bank 2r -> distinct)

typedef _Float16 v4h __attribute__((ext_vector_type(4)));
typedef float    v4f __attribute__((ext_vector_type(4)));

#define MFMA(a, b, c) __builtin_amdgcn_mfma_f32_16x16x16f16((a), (b), (c), 0, 0, 0)

union HU { unsigned u[2]; v4h h; };

__device__ __forceinline__ v4h zero4h() {
    v4h z; z[0] = z[1] = z[2] = z[3] = (_Float16)0.f; return z;
}
__device__ __forceinline__ v4h afragT(const float* __restrict__ W, int ncols, int co,
                                      int kin, int k0, int lane, int colmax) {
    const int mm = lane & 15, gg = lane >> 4;
    v4h r;
    #pragma unroll
    for (int j = 0; j < 4; ++j) {
        const int k = k0 + 4 * gg + j;
        const float v = (k < kin && (co + mm) < colmax) ? W[k * ncols + co + mm] : 0.f;
        r[j] = (_Float16)v;
    }
    return r;
}
__device__ __forceinline__ v4f bfrag4(const float* __restrict__ b, int gg) {
    const float4 t = *(const float4*)(b + 4 * gg);
    v4f r; r[0] = t.x; r[1] = t.y; r[2] = t.z; r[3] = t.w; return r;
}
__device__ __forceinline__ v4h packR(v4f d) {
    v4h r;
    #pragma unroll
    for (int j = 0; j < 4; ++j) r[j] = (_Float16)fmaxf(d[j], 0.f);
    return r;
}
__device__ __forceinline__ v4h packL(v4f d) {
    v4h r;
    #pragma unroll
    for (int j = 0; j < 4; ++j) { const float a = d[j]; r[j] = (_Float16)fmaxf(a, 0.01f * a); }
    return r;
}
__device__ __forceinline__ v4f relu4(v4f d) {
    v4f r;
    #pragma unroll
    for (int j = 0; j < 4; ++j) r[j] = fmaxf(d[j], 0.f);
    return r;
}
__device__ __forceinline__ float fast_tanh(float x) {
    x = fminf(fmaxf(x, -15.f), 15.f);
    const float ex = __expf(2.f * x);
    return (ex - 1.f) / (ex + 1.f);
}

__global__ __launch_bounds__(64)
void actor_mfma(const float* __restrict__ x,
                const float* __restrict__ en_w1, const float* __restrict__ en_b1,
                const float* __restrict__ en_w2, const float* __restrict__ en_b2,
                const float* __restrict__ oa_w1, const float* __restrict__ oa_b1,
                const float* __restrict__ oa_w2, const float* __restrict__ oa_b2,
                const float* __restrict__ oa_g,  const float* __restrict__ oa_bln,
                const float* __restrict__ g_w1,  const float* __restrict__ g_b1,
                const float* __restrict__ g_w2,  const float* __restrict__ g_b2,
                const float* __restrict__ g_g,   const float* __restrict__ g_bln,
                const float* __restrict__ m_w1,  const float* __restrict__ m_b1,
                const float* __restrict__ m_w2,  const float* __restrict__ m_b2,
                const float* __restrict__ m_w3,  const float* __restrict__ m_b3,
                float* __restrict__ out, int B)
{
    const int lane = threadIdx.x;
    const int mm = lane & 15, gg = lane >> 4;

    __shared__ __align__(16) _Float16 xs[16 * XSS];

    // ---- all weight fragments + hot biases: once per wave (64 rows) ----
    const v4h ew1t0 = afragT(en_w1, 32, 0, 4, 0, lane, 32);
    const v4h ew1t1 = afragT(en_w1, 32, 16, 4, 0, lane, 32);
    const v4h ew2k0 = afragT(en_w2, 16, 0, 32, 0, lane, 16);
    const v4h ew2k1 = afragT(en_w2, 16, 0, 32, 16, lane, 16);
    const v4f eb1t0 = bfrag4(en_b1, gg);
    const v4f eb1t1 = bfrag4(en_b1 + 16, gg);
    const v4f eb2   = bfrag4(en_b2, gg);

    const v4h ow1t0 = afragT(oa_w1, 32, 0, 5, 0, lane, 32);
    const v4h ow1t1 = afragT(oa_w1, 32, 16, 5, 0, lane, 32);
    const v4h ow2k0 = afragT(oa_w2, 16, 0, 32, 0, lane, 16);
    const v4h ow2k1 = afragT(oa_w2, 16, 0, 32, 16, lane, 16);
    const v4f ob1t0 = bfrag4(oa_b1, gg);
    const v4f ob1t1 = bfrag4(oa_b1 + 16, gg);
    const v4f ob2   = bfrag4(oa_b2, gg);
    const v4f ogf   = bfrag4(oa_g, gg);
    const v4f obl   = bfrag4(oa_bln, gg);

    const v4h fw1t0 = afragT(g_w1, 32, 0, 3, 0, lane, 32);
    const v4h fw1t1 = afragT(g_w1, 32, 16, 3, 0, lane, 32);
    const v4h fw2k0 = afragT(g_w2, 16, 0, 32, 0, lane, 16);
    const v4h fw2k1 = afragT(g_w2, 16, 0, 32, 16, lane, 16);
    const v4f fb1t0 = bfrag4(g_b1, gg);
    const v4f fb1t1 = bfrag4(g_b1 + 16, gg);
    const v4f fb2   = bfrag4(g_b2, gg);
    const v4f fgf   = bfrag4(g_g, gg);
    const v4f fbl   = bfrag4(g_bln, gg);

    const v4h mA00 = afragT(m_w1, 32, 0, 48, 0, lane, 32);
    const v4h mA01 = afragT(m_w1, 32, 0, 48, 16, lane, 32);
    const v4h mA02 = afragT(m_w1, 32, 0, 48, 32, lane, 32);
    const v4h mA10 = afragT(m_w1, 32, 16, 48, 0, lane, 32);
    const v4h mA11 = afragT(m_w1, 32, 16, 48, 16, lane, 32);
    const v4h mA12 = afragT(m_w1, 32, 16, 48, 32, lane, 32);
    const v4h mB00 = afragT(m_w2, 32, 0, 32, 0, lane, 32);
    const v4h mB01 = afragT(m_w2, 32, 0, 32, 16, lane, 32);
    const v4h mB10 = afragT(m_w2, 32, 16, 32, 0, lane, 32);
    const v4h mB11 = afragT(m_w2, 32, 16, 32, 16, lane, 32);
    const v4h mC0  = afragT(m_w3, 2, 0, 32, 0, lane, 2);
    const v4h mC1  = afragT(m_w3, 2, 0, 32, 16, lane, 2);

    const int base = blockIdx.x * 64;

    for (int grp = 0; grp < 4; ++grp) {
        const int r0 = base + grp * 16;
        if (r0 >= B) break;

        // ---- stage 16 rows as f16 (coalesced dword reads) ----
        {
            const float* __restrict__ xp = x + (size_t)r0 * OBS;
            const int lim = (r0 + 16 <= B) ? 2032 : (B - r0) * OBS;
            #pragma unroll
            for (int i = 0; i < 32; ++i) {
                const int f = i * 64 + lane;
                if (f < lim) {
                    const int r = f / 127;            // magic-mul
                    xs[f + 5 * r] = (_Float16)xp[f];  // row*132 + col
                }
            }
        }
        __syncthreads();   // 1 wave: waitcnt only

        // ---- self encoder (N=row) ----
        v4h bs = zero4h();
        if (gg == 0) bs = *(const v4h*)(xs + mm * XSS);
        const v4f h0 = MFMA(ew1t0, bs, eb1t0);
        const v4f h1 = MFMA(ew1t1, bs, eb1t1);
        v4f st = MFMA(ew2k0, packR(h0), eb2);
        st = MFMA(ew2k1, packR(h1), st);
        st = relu4(st);
        const v4h Bself = packR(st);

        // ---- fused entity loop: food (16) + other (15) interleaved ----
        const _Float16* xr = xs + mm * XSS;
        float mo = -3.0e38f, lo = 0.f, oo0 = 0.f, oo1 = 0.f, oo2 = 0.f, oo3 = 0.f;
        float mf = -3.0e38f, lf = 0.f, of0 = 0.f, of1 = 0.f, of2 = 0.f, of3 = 0.f;
        #pragma unroll 4
        for (int e = 0; e < 16; ++e) {
            // food entity e
            {
                v4h bfr = zero4h();
                if (gg == 0) {
                    bfr[0] = xr[79 + 3 * e];
                    bfr[1] = xr[80 + 3 * e];
                    bfr[2] = xr[81 + 3 * e];
                }
                const v4f d0 = MFMA(fw1t0, bfr, fb1t0);
                const v4f d1 = MFMA(fw1t1, bfr, fb1t1);
                v4f e2 = MFMA(fw2k0, packR(d0), fb2);
                e2 = MFMA(fw2k1, packR(d1), e2);
                e2 = relu4(e2);
                float part = st[0] * e2[0] + st[1] * e2[1] + st[2] * e2[2] + st[3] * e2[3];
                part += __shfl_xor(part, 16);
                part += __shfl_xor(part, 32);
                const float s = part * 0.25f;
                const float d = mf - s;
                const float mn = fmaxf(mf, s);
                const float ee = __expf(-fabsf(d));
                const float sc = (d < 0.f) ? ee : 1.f;
                const float p  = (d < 0.f) ? 1.f : ee;
                lf = lf * sc + p;
                of0 = of0 * sc + p * e2[0];
                of1 = of1 * sc + p * e2[1];
                of2 = of2 * sc + p * e2[2];
                of3 = of3 * sc + p * e2[3];
                mf = mn;
            }
            // other entity e (15 only)
            if (e < 15) {
                v4h bfr = zero4h();
                if (gg == 0) {
                    HU u;
                    u.u[0] = *(const unsigned*)(xr + 4 + 2 * e);
                    u.u[1] = *(const unsigned*)(xr + 34 + 2 * e);
                    bfr = u.h;
                } else if (gg == 1) {
                    bfr[0] = xr[64 + e];
                }
                const v4f d0 = MFMA(ow1t0, bfr, ob1t0);
                const v4f d1 = MFMA(ow1t1, bfr, ob1t1);
                v4f e2 = MFMA(ow2k0, packR(d0), ob2);
                e2 = MFMA(ow2k1, packR(d1), e2);
                e2 = relu4(e2);
                float part = st[0] * e2[0] + st[1] * e2[1] + st[2] * e2[2] + st[3] * e2[3];
                part += __shfl_xor(part, 16);
                part += __shfl_xor(part, 32);
                const float s = part * 0.25f;
                const float d = mo - s;
                const float mn = fmaxf(mo, s);
                const float ee = __expf(-fabsf(d));
                const float sc = (d < 0.f) ? ee : 1.f;
                const float p  = (d < 0.f) ? 1.f : ee;
                lo = lo * sc + p;
                oo0 = oo0 * sc + p * e2[0];
                oo1 = oo1 * sc + p * e2[1];
                oo2 = oo2 * sc + p * e2[2];
                oo3 = oo3 * sc + p * e2[3];
                mo = mn;
            }
        }

        // ---- finalize both branches: normalize + LN + affine + relu ----
        v4h Bfood, Bother;
        {
            const float rl = 1.f / lf;
            float a0 = of0 * rl, a1 = of1 * rl, a2 = of2 * rl, a3 = of3 * rl;
            float sum = a0 + a1 + a2 + a3;
            sum += __shfl_xor(sum, 16); sum += __shfl_xor(sum, 32);
            const float mu = sum * 0.0625f;
            const float e0 = a0 - mu, e1 = a1 - mu, e2c = a2 - mu, e3 = a3 - mu;
            float vv = e0 * e0 + e1 * e1 + e2c * e2c + e3 * e3;
            vv += __shfl_xor(vv, 16); vv += __shfl_xor(vv, 32);
            const float inv = rsqrtf(vv * 0.0625f + 1e-5f);
            Bfood[0] = (_Float16)fmaxf(e0 * inv * fgf[0] + fbl[0], 0.f);
            Bfood[1] = (_Float16)fmaxf(e1 * inv * fgf[1] + fbl[1], 0.f);
            Bfood[2] = (_Float16)fmaxf(e2c * inv * fgf[2] + fbl[2], 0.f);
            Bfood[3] = (_Float16)fmaxf(e3 * inv * fgf[3] + fbl[3], 0.f);
        }
        {
            const float rl = 1.f / lo;
            float a0 = oo0 * rl, a1 = oo1 * rl, a2 = oo2 * rl, a3 = oo3 * rl;
            float sum = a0 + a1 + a2 + a3;
            sum += __shfl_xor(sum, 16); sum += __shfl_xor(sum, 32);
            const float mu = sum * 0.0625f;
            const float e0 = a0 - mu, e1 = a1 - mu, e2c = a2 - mu, e3 = a3 - mu;
            float vv = e0 * e0 + e1 * e1 + e2c * e2c + e3 * e3;
            vv += __shfl_xor(vv, 16); vv += __shfl_xor(vv, 32);
            const float inv = rsqrtf(vv * 0.0625f + 1e-5f);
            Bother[0] = (_Float16)fmaxf(e0 * inv * ogf[0] + obl[0], 0.f);
            Bother[1] = (_Float16)fmaxf(e1 * inv * ogf[1] + obl[1], 0.f);
            Bother[2] = (_Float16)fmaxf(e2c * inv * ogf[2] + obl[2], 0.f);
            Bother[3] = (_Float16)fmaxf(e3 * inv * ogf[3] + obl[3], 0.f);
        }

        // ---- merge MLP (N=row): 48 -> 32 lrelu -> 32 lrelu -> 2 tanh ----
        v4f h1t0 = bfrag4(m_b1, gg);
        v4f h1t1 = bfrag4(m_b1 + 16, gg);
        h1t0 = MFMA(mA00, Bself, h1t0);
        h1t0 = MFMA(mA01, Bfood, h1t0);
        h1t0 = MFMA(mA02, Bother, h1t0);
        h1t1 = MFMA(mA10, Bself, h1t1);
        h1t1 = MFMA(mA11, Bfood, h1t1);
        h1t1 = MFMA(mA12, Bother, h1t1);
        const v4h q0 = packL(h1t0), q1 = packL(h1t1);
        v4f h2t0 = bfrag4(m_b2, gg);
        v4f h2t1 = bfrag4(m_b2 + 16, gg);
        h2t0 = MFMA(mB00, q0, h2t0);
        h2t0 = MFMA(mB01, q1, h2t0);
        h2t1 = MFMA(mB10, q0, h2t1);
        h2t1 = MFMA(mB11, q1, h2t1);
        const v4h z0 = packL(h2t0), z1 = packL(h2t1);
        v4f ob; ob[0] = ob[1] = ob[2] = ob[3] = 0.f;
        if (gg == 0) { ob[0] = m_b3[0]; ob[1] = m_b3[1]; }
        v4f oo = MFMA(mC0, z0, ob);
        oo = MFMA(mC1, z1, oo);

        if (gg == 0 && r0 + mm < B) {
            float2 res;
            res.x = fast_tanh(oo[0]);
            res.y = fast_tanh(oo[1]);
            *(float2*)(out + (size_t)(r0 + mm) * 2) = res;
        }
        __syncthreads();   // protect xs before next group's staging
    }
}

extern "C" void kernel_launch(void* const* d_in, const int* in_sizes, int n_in,
                              void* d_out, int out_size, void* d_ws, size_t ws_size,
                              hipStream_t stream) {
    const int B = in_sizes[0] / OBS;
    const float* xin = (const float*)d_in[0];
    const float* en_w1 = (const float*)d_in[1];
    const float* en_b1 = (const float*)d_in[2];
    const float* en_w2 = (const float*)d_in[3];
    const float* en_b2 = (const float*)d_in[4];
    const float* oa_w1 = (const float*)d_in[5];
    const float* oa_b1 = (const float*)d_in[6];
    const float* oa_w2 = (const float*)d_in[7];
    const float* oa_b2 = (const float*)d_in[8];
    const float* oa_g  = (const float*)d_in[9];
    const float* oa_bl = (const float*)d_in[10];
    const float* g_w1  = (const float*)d_in[11];
    const float* g_b1  = (const float*)d_in[12];
    const float* g_w2  = (const float*)d_in[13];
    const float* g_b2  = (const float*)d_in[14];
    const float* g_g   = (const float*)d_in[15];
    const float* g_bl  = (const float*)d_in[16];
    const float* m_w1  = (const float*)d_in[17];
    const float* m_b1  = (const float*)d_in[18];
    const float* m_w2  = (const float*)d_in[19];
    const float* m_b2  = (const float*)d_in[20];
    const float* m_w3  = (const float*)d_in[21];
    const float* m_b3  = (const float*)d_in[22];

    const int rows_per_block = 64;   // 1 wave x 4 groups x 16 rows
    const int grid = (B + rows_per_block - 1) / rows_per_block;
    actor_mfma<<<grid, 64, 0, stream>>>(
        xin, en_w1, en_b1, en_w2, en_b2,
        oa_w1, oa_b1, oa_w2, oa_b2, oa_g, oa_bl,
        g_w1, g_b1, g_w2, g_b2, g_g, g_bl,
        m_w1, m_b1, m_w2, m_b2, m_w3, m_b3,
        (float*)d_out, B);
}

// Round 6
// 385.536 us; speedup vs baseline: 1.1539x; 1.1539x over previous
//
#include <hip/hip_runtime.h>
#include <math.h>

// Actor_att1 on gfx950 — R6 (R5 + cvt_pkrtz type fix).
// 256-thread blocks (4 waves); each wave owns a private LDS slice and
// processes 4 groups x 16 rows = 64 rows (setup amortized, R3 occupancy).
// Entity loop: fused food+other, softmax without max-subtraction
// (exp2-folded scale; scale-invariant => identical math), pkrtz packs.
// Fragment conventions HW-validated in R2/R3/R4 (absmax 1.95e-3).

#define OBS 127
#define XSS 132   // f16 LDS row stride

typedef _Float16 v4h __attribute__((ext_vector_type(4)));
typedef __fp16   p2h __attribute__((ext_vector_type(2)));   // cvt_pkrtz result type
typedef float    v4f __attribute__((ext_vector_type(4)));
typedef float    f4u __attribute__((ext_vector_type(4), aligned(4)));

#define MFMA(a, b, c) __builtin_amdgcn_mfma_f32_16x16x16f16((a), (b), (c), 0, 0, 0)

union HU { unsigned u[2]; v4h h; };
union PK { p2h p[2]; v4h h; uint2 u; };

__device__ __forceinline__ v4h zero4h() {
    v4h z; z[0] = z[1] = z[2] = z[3] = (_Float16)0.f; return z;
}
__device__ __forceinline__ v4h afragT(const float* __restrict__ W, int ncols, int co,
                                      int kin, int k0, int lane, int colmax) {
    const int mm = lane & 15, gg = lane >> 4;
    v4h r;
    #pragma unroll
    for (int j = 0; j < 4; ++j) {
        const int k = k0 + 4 * gg + j;
        const float v = (k < kin && (co + mm) < colmax) ? W[k * ncols + co + mm] : 0.f;
        r[j] = (_Float16)v;
    }
    return r;
}
__device__ __forceinline__ v4f bfrag4(const float* __restrict__ b, int gg) {
    const float4 t = *(const float4*)(b + 4 * gg);
    v4f r; r[0] = t.x; r[1] = t.y; r[2] = t.z; r[3] = t.w; return r;
}
__device__ __forceinline__ v4h pkR(v4f d) {   // relu + packed cvt (RTZ)
    PK q;
    q.p[0] = __builtin_amdgcn_cvt_pkrtz(fmaxf(d[0], 0.f), fmaxf(d[1], 0.f));
    q.p[1] = __builtin_amdgcn_cvt_pkrtz(fmaxf(d[2], 0.f), fmaxf(d[3], 0.f));
    return q.h;
}
__device__ __forceinline__ v4h pkL(v4f d) {   // leaky-relu + packed cvt
    PK q;
    const float a0 = fmaxf(d[0], 0.01f * d[0]), a1 = fmaxf(d[1], 0.01f * d[1]);
    const float a2 = fmaxf(d[2], 0.01f * d[2]), a3 = fmaxf(d[3], 0.01f * d[3]);
    q.p[0] = __builtin_amdgcn_cvt_pkrtz(a0, a1);
    q.p[1] = __builtin_amdgcn_cvt_pkrtz(a2, a3);
    return q.h;
}
__device__ __forceinline__ v4f relu4(v4f d) {
    v4f r;
    #pragma unroll
    for (int j = 0; j < 4; ++j) r[j] = fmaxf(d[j], 0.f);
    return r;
}
__device__ __forceinline__ float fast_tanh(float x) {
    x = fminf(fmaxf(x, -15.f), 15.f);
    const float ex = __expf(2.f * x);
    return (ex - 1.f) / (ex + 1.f);
}
// LN over 16 ch (4 per lane x 4 gg-groups) + affine + relu + pack
__device__ __forceinline__ v4h ln_pack(float a0, float a1, float a2, float a3,
                                       v4f gf, v4f bl) {
    float sum = a0 + a1 + a2 + a3;
    sum += __shfl_xor(sum, 16); sum += __shfl_xor(sum, 32);
    const float mu = sum * 0.0625f;
    const float e0 = a0 - mu, e1 = a1 - mu, e2 = a2 - mu, e3 = a3 - mu;
    float vv = e0 * e0 + e1 * e1 + e2 * e2 + e3 * e3;
    vv += __shfl_xor(vv, 16); vv += __shfl_xor(vv, 32);
    const float inv = rsqrtf(vv * 0.0625f + 1e-5f);
    PK q;
    q.p[0] = __builtin_amdgcn_cvt_pkrtz(fmaxf(e0 * inv * gf[0] + bl[0], 0.f),
                                        fmaxf(e1 * inv * gf[1] + bl[1], 0.f));
    q.p[1] = __builtin_amdgcn_cvt_pkrtz(fmaxf(e2 * inv * gf[2] + bl[2], 0.f),
                                        fmaxf(e3 * inv * gf[3] + bl[3], 0.f));
    return q.h;
}

__global__ __launch_bounds__(256)
void actor_mfma(const float* __restrict__ x,
                const float* __restrict__ en_w1, const float* __restrict__ en_b1,
                const float* __restrict__ en_w2, const float* __restrict__ en_b2,
                const float* __restrict__ oa_w1, const float* __restrict__ oa_b1,
                const float* __restrict__ oa_w2, const float* __restrict__ oa_b2,
                const float* __restrict__ oa_g,  const float* __restrict__ oa_bln,
                const float* __restrict__ g_w1,  const float* __restrict__ g_b1,
                const float* __restrict__ g_w2,  const float* __restrict__ g_b2,
                const float* __restrict__ g_g,   const float* __restrict__ g_bln,
                const float* __restrict__ m_w1,  const float* __restrict__ m_b1,
                const float* __restrict__ m_w2,  const float* __restrict__ m_b2,
                const float* __restrict__ m_w3,  const float* __restrict__ m_b3,
                float* __restrict__ out, int B)
{
    const int lane = threadIdx.x & 63, wid = threadIdx.x >> 6;
    const int mm = lane & 15, gg = lane >> 4;

    __shared__ __align__(16) _Float16 xs_all[4][16 * XSS];
    _Float16* xs = xs_all[wid];   // private per-wave slice

    // ---- weight fragments: once per wave (serve 64 rows) ----
    const v4h ew1t0 = afragT(en_w1, 32, 0, 4, 0, lane, 32);
    const v4h ew1t1 = afragT(en_w1, 32, 16, 4, 0, lane, 32);
    const v4h ew2k0 = afragT(en_w2, 16, 0, 32, 0, lane, 16);
    const v4h ew2k1 = afragT(en_w2, 16, 0, 32, 16, lane, 16);
    const v4f eb1t0 = bfrag4(en_b1, gg);
    const v4f eb1t1 = bfrag4(en_b1 + 16, gg);
    const v4f eb2   = bfrag4(en_b2, gg);

    const v4h ow1t0 = afragT(oa_w1, 32, 0, 5, 0, lane, 32);
    const v4h ow1t1 = afragT(oa_w1, 32, 16, 5, 0, lane, 32);
    const v4h ow2k0 = afragT(oa_w2, 16, 0, 32, 0, lane, 16);
    const v4h ow2k1 = afragT(oa_w2, 16, 0, 32, 16, lane, 16);
    const v4f ob1t0 = bfrag4(oa_b1, gg);
    const v4f ob1t1 = bfrag4(oa_b1 + 16, gg);
    const v4f ob2   = bfrag4(oa_b2, gg);

    const v4h fw1t0 = afragT(g_w1, 32, 0, 3, 0, lane, 32);
    const v4h fw1t1 = afragT(g_w1, 32, 16, 3, 0, lane, 32);
    const v4h fw2k0 = afragT(g_w2, 16, 0, 32, 0, lane, 16);
    const v4h fw2k1 = afragT(g_w2, 16, 0, 32, 16, lane, 16);
    const v4f fb1t0 = bfrag4(g_b1, gg);
    const v4f fb1t1 = bfrag4(g_b1 + 16, gg);
    const v4f fb2   = bfrag4(g_b2, gg);

    const v4h mA00 = afragT(m_w1, 32, 0, 48, 0, lane, 32);
    const v4h mA01 = afragT(m_w1, 32, 0, 48, 16, lane, 32);
    const v4h mA02 = afragT(m_w1, 32, 0, 48, 32, lane, 32);
    const v4h mA10 = afragT(m_w1, 32, 16, 48, 0, lane, 32);
    const v4h mA11 = afragT(m_w1, 32, 16, 48, 16, lane, 32);
    const v4h mA12 = afragT(m_w1, 32, 16, 48, 32, lane, 32);
    const v4h mB00 = afragT(m_w2, 32, 0, 32, 0, lane, 32);
    const v4h mB01 = afragT(m_w2, 32, 0, 32, 16, lane, 32);
    const v4h mB10 = afragT(m_w2, 32, 16, 32, 0, lane, 32);
    const v4h mB11 = afragT(m_w2, 32, 16, 32, 16, lane, 32);
    const v4h mC0  = afragT(m_w3, 2, 0, 32, 0, lane, 2);
    const v4h mC1  = afragT(m_w3, 2, 0, 32, 16, lane, 2);

    const int base = blockIdx.x * 256 + wid * 64;

    #pragma clang loop unroll(disable)
    for (int grp = 0; grp < 4; ++grp) {
        const int r0 = base + grp * 16;
        if (r0 >= B) break;

        // ---- stage 16 rows as f16: float4 loads + b64 LDS writes ----
        {
            const float* __restrict__ xp = x + (size_t)r0 * OBS;
            if (r0 + 16 <= B) {
                #pragma unroll
                for (int i = 0; i < 8; ++i) {
                    const int g = i * 64 + lane;
                    if (g < 496) {                   // 16 rows x 31 float4 (cols 0..123)
                        const int row = g / 31;      // magic-mul
                        const int c4 = g - row * 31;
                        const f4u v = *(const f4u*)(xp + row * 127 + c4 * 4);
                        PK q;
                        q.p[0] = __builtin_amdgcn_cvt_pkrtz(v[0], v[1]);
                        q.p[1] = __builtin_amdgcn_cvt_pkrtz(v[2], v[3]);
                        *(uint2*)(xs + row * XSS + c4 * 4) = q.u;  // 8B-aligned
                    }
                }
                if (lane < 48) {                     // tail cols 124..126
                    const int row = lane / 3;
                    const int c = 124 + lane - row * 3;
                    xs[row * XSS + c] = (_Float16)xp[row * 127 + c];
                }
            } else {                                 // ragged tail block
                const int lim = (B - r0) * OBS;
                for (int i = 0; i < 32; ++i) {
                    const int f = i * 64 + lane;
                    if (f < lim) {
                        const int r = f / 127;
                        xs[f + 5 * r] = (_Float16)xp[f];
                    }
                }
            }
        }
        __syncthreads();

        // ---- self encoder (N=row) ----
        v4h bs = zero4h();
        if (gg == 0) bs = *(const v4h*)(xs + mm * XSS);
        const v4f h0 = MFMA(ew1t0, bs, eb1t0);
        const v4f h1 = MFMA(ew1t1, bs, eb1t1);
        v4f st = MFMA(ew2k0, pkR(h0), eb2);
        st = MFMA(ew2k1, pkR(h1), st);
        st = relu4(st);
        const v4h Bself = pkR(st);
        // pre-scaled for score: 0.25 (1/sqrt16) * log2(e), exp via exp2
        const float SK = 0.25f * 1.44269504088896f;
        const v4f stl = { st[0] * SK, st[1] * SK, st[2] * SK, st[3] * SK };

        // ---- fused entity loop (no max-subtraction: softmax scale-invariant) ----
        const _Float16* xr = xs + mm * XSS;
        float lf = 0.f, of0 = 0.f, of1 = 0.f, of2 = 0.f, of3 = 0.f;
        float lo = 0.f, oo0 = 0.f, oo1 = 0.f, oo2 = 0.f, oo3 = 0.f;
        #pragma unroll 4
        for (int e = 0; e < 16; ++e) {
            {   // food entity e
                v4h bfr = zero4h();
                if (gg == 0) {
                    bfr[0] = xr[79 + 3 * e];
                    bfr[1] = xr[80 + 3 * e];
                    bfr[2] = xr[81 + 3 * e];
                }
                const v4f d0 = MFMA(fw1t0, bfr, fb1t0);
                const v4f d1 = MFMA(fw1t1, bfr, fb1t1);
                v4f e2 = MFMA(fw2k0, pkR(d0), fb2);
                e2 = MFMA(fw2k1, pkR(d1), e2);
                e2 = relu4(e2);
                float part = stl[0] * e2[0] + stl[1] * e2[1] + stl[2] * e2[2] + stl[3] * e2[3];
                part += __shfl_xor(part, 16);
                part += __shfl_xor(part, 32);
                const float p = exp2f(part);
                lf += p;
                of0 += p * e2[0]; of1 += p * e2[1];
                of2 += p * e2[2]; of3 += p * e2[3];
            }
            if (e < 15) {   // other entity e
                v4h bfr = zero4h();
                if (gg == 0) {
                    HU u;
                    u.u[0] = *(const unsigned*)(xr + 4 + 2 * e);
                    u.u[1] = *(const unsigned*)(xr + 34 + 2 * e);
                    bfr = u.h;
                } else if (gg == 1) {
                    bfr[0] = xr[64 + e];
                }
                const v4f d0 = MFMA(ow1t0, bfr, ob1t0);
                const v4f d1 = MFMA(ow1t1, bfr, ob1t1);
                v4f e2 = MFMA(ow2k0, pkR(d0), ob2);
                e2 = MFMA(ow2k1, pkR(d1), e2);
                e2 = relu4(e2);
                float part = stl[0] * e2[0] + stl[1] * e2[1] + stl[2] * e2[2] + stl[3] * e2[3];
                part += __shfl_xor(part, 16);
                part += __shfl_xor(part, 32);
                const float p = exp2f(part);
                lo += p;
                oo0 += p * e2[0]; oo1 += p * e2[1];
                oo2 += p * e2[2]; oo3 += p * e2[3];
            }
        }

        // ---- finalize branches (normalize, LN, affine, relu) ----
        const float rlf = 1.f / lf;
        const v4h Bfood = ln_pack(of0 * rlf, of1 * rlf, of2 * rlf, of3 * rlf,
                                  bfrag4(g_g, gg), bfrag4(g_bln, gg));
        const float rlo = 1.f / lo;
        const v4h Bother = ln_pack(oo0 * rlo, oo1 * rlo, oo2 * rlo, oo3 * rlo,
                                   bfrag4(oa_g, gg), bfrag4(oa_bln, gg));

        // ---- merge MLP (N=row): 48 -> 32 lrelu -> 32 lrelu -> 2 tanh ----
        v4f h1t0 = bfrag4(m_b1, gg);
        v4f h1t1 = bfrag4(m_b1 + 16, gg);
        h1t0 = MFMA(mA00, Bself, h1t0);
        h1t0 = MFMA(mA01, Bfood, h1t0);
        h1t0 = MFMA(mA02, Bother, h1t0);
        h1t1 = MFMA(mA10, Bself, h1t1);
        h1t1 = MFMA(mA11, Bfood, h1t1);
        h1t1 = MFMA(mA12, Bother, h1t1);
        const v4h q0 = pkL(h1t0), q1 = pkL(h1t1);
        v4f h2t0 = bfrag4(m_b2, gg);
        v4f h2t1 = bfrag4(m_b2 + 16, gg);
        h2t0 = MFMA(mB00, q0, h2t0);
        h2t0 = MFMA(mB01, q1, h2t0);
        h2t1 = MFMA(mB10, q0, h2t1);
        h2t1 = MFMA(mB11, q1, h2t1);
        const v4h z0 = pkL(h2t0), z1 = pkL(h2t1);
        v4f ob; ob[0] = ob[1] = ob[2] = ob[3] = 0.f;
        if (gg == 0) { ob[0] = m_b3[0]; ob[1] = m_b3[1]; }
        v4f oo = MFMA(mC0, z0, ob);
        oo = MFMA(mC1, z1, oo);

        if (gg == 0 && r0 + mm < B) {
            float2 res;
            res.x = fast_tanh(oo[0]);
            res.y = fast_tanh(oo[1]);
            *(float2*)(out + (size_t)(r0 + mm) * 2) = res;
        }
        __syncthreads();
    }
}

extern "C" void kernel_launch(void* const* d_in, const int* in_sizes, int n_in,
                              void* d_out, int out_size, void* d_ws, size_t ws_size,
                              hipStream_t stream) {
    const int B = in_sizes[0] / OBS;
    const float* xin = (const float*)d_in[0];
    const float* en_w1 = (const float*)d_in[1];
    const float* en_b1 = (const float*)d_in[2];
    const float* en_w2 = (const float*)d_in[3];
    const float* en_b2 = (const float*)d_in[4];
    const float* oa_w1 = (const float*)d_in[5];
    const float* oa_b1 = (const float*)d_in[6];
    const float* oa_w2 = (const float*)d_in[7];
    const float* oa_b2 = (const float*)d_in[8];
    const float* oa_g  = (const float*)d_in[9];
    const float* oa_bl = (const float*)d_in[10];
    const float* g_w1  = (const float*)d_in[11];
    const float* g_b1  = (const float*)d_in[12];
    const float* g_w2  = (const float*)d_in[13];
    const float* g_b2  = (const float*)d_in[14];
    const float* g_g   = (const float*)d_in[15];
    const float* g_bl  = (const float*)d_in[16];
    const float* m_w1  = (const float*)d_in[17];
    const float* m_b1  = (const float*)d_in[18];
    const float* m_w2  = (const float*)d_in[19];
    const float* m_b2  = (const float*)d_in[20];
    const float* m_w3  = (const float*)d_in[21];
    const float* m_b3  = (const float*)d_in[22];

    const int rows_per_block = 256;  // 4 waves x 4 groups x 16 rows
    const int grid = (B + rows_per_block - 1) / rows_per_block;
    actor_mfma<<<grid, 256, 0, stream>>>(
        xin, en_w1, en_b1, en_w2, en_b2,
        oa_w1, oa_b1, oa_w2, oa_b2, oa_g, oa_bl,
        g_w1, g_b1, g_w2, g_b2, g_g, g_bl,
        m_w1, m_b1, m_w2, m_b2, m_w3, m_b3,
        (float*)d_out, B);
}

// Round 7
// 304.430 us; speedup vs baseline: 1.4613x; 1.2664x over previous
//
#include <hip/hip_runtime.h>
#include <math.h>

// Actor_att1 on gfx950 — R7: 32x32x8 MFMA retile, one wave = 32 rows.
// D layout (n=lane&31, m=(r&3)+8*(r>>2)+4*(lane>>5); m74/m101-verified) has
// D->B duality: packed D regs [4s..4s+3] = B chunk s (k=8s+4*(lane>>5)+j).
// L1 biases folded as constant-1 feature in K-slack. 1 shuffle per reduce.

#define OBS 127
#define XSS 132   // f16 LDS row stride (264B: row n base bank = 2n)

typedef _Float16 v4h  __attribute__((ext_vector_type(4)));
typedef __fp16   p2h  __attribute__((ext_vector_type(2)));
typedef float    v16f __attribute__((ext_vector_type(16)));
typedef float    f4u  __attribute__((ext_vector_type(4), aligned(4)));

#define MFMA32(a, b, c) __builtin_amdgcn_mfma_f32_32x32x8f16((a), (b), (c), 0, 0, 0)

union PK { p2h p[2]; v4h h; uint2 u; };
union HU { unsigned u[2]; v4h h; };

__device__ __forceinline__ v4h zero4h() {
    v4h z; z[0] = z[1] = z[2] = z[3] = (_Float16)0.f; return z;
}
__device__ __forceinline__ v4h pack4(float a, float b, float c, float d) {
    PK q;
    q.p[0] = __builtin_amdgcn_cvt_pkrtz(a, b);
    q.p[1] = __builtin_amdgcn_cvt_pkrtz(c, d);
    return q.h;
}
// L1 A-frag: W (kin x 32) + bias row at k==kin. A[m=lane&31][k=4h+j].
__device__ __forceinline__ v4h a1frag(const float* __restrict__ W,
                                      const float* __restrict__ b,
                                      int kin, int m, int h) {
    v4h r;
    #pragma unroll
    for (int j = 0; j < 4; ++j) {
        const int k = 4 * h + j;
        const float v = (k < kin) ? W[k * 32 + m] : (k == kin ? b[m] : 0.f);
        r[j] = (_Float16)v;
    }
    return r;
}
// L2 A chunk s: W2 (32 x 16). k=8s+4h+j, m<16 else 0.
__device__ __forceinline__ v4h a2frag(const float* __restrict__ W2,
                                      int s, int m, int h) {
    v4h r;
    #pragma unroll
    for (int j = 0; j < 4; ++j) {
        const int k = 8 * s + 4 * h + j;
        r[j] = (_Float16)((m < 16) ? W2[k * 16 + m] : 0.f);
    }
    return r;
}
// merge W chunk: W (K x ncols), m<colmax.
__device__ __forceinline__ v4h wfrag(const float* __restrict__ W, int ncols,
                                     int K, int s, int m, int h, int colmax) {
    v4h r;
    #pragma unroll
    for (int j = 0; j < 4; ++j) {
        const int k = 8 * s + 4 * h + j;
        r[j] = (_Float16)((k < K && m < colmax) ? W[k * ncols + m] : 0.f);
    }
    return r;
}
// bias A chunk: (h==0,j==0) -> b[m]
__device__ __forceinline__ v4h bfragA(const float* __restrict__ b, int m, int h, int colmax) {
    v4h r = zero4h();
    if (h == 0 && m < colmax) r[0] = (_Float16)b[m];
    return r;
}
__device__ __forceinline__ float fast_tanh(float x) {
    x = fminf(fmaxf(x, -15.f), 15.f);
    const float ex = __expf(2.f * x);
    return (ex - 1.f) / (ex + 1.f);
}

// One entity through its 2-layer encoder + online softmax accumulate.
// BR=0: other (5 feat + bias), BR=1: food (3 feat + bias).
template <int BR>
__device__ __forceinline__ void entity_step(const _Float16* __restrict__ xr,
                                            int e, int h,
                                            v4h A1, const v4h (&A2)[4],
                                            const float (&b2v)[8],
                                            const float (&stl)[8],
                                            float& l, float (&o)[8],
                                            v16f z16) {
    v4h bf = zero4h();
    if (BR == 1) {
        if (h == 0) {
            bf[0] = xr[79 + 3 * e];
            bf[1] = xr[80 + 3 * e];
            bf[2] = xr[81 + 3 * e];
            bf[3] = (_Float16)1.f;           // k=3 = bias feature
        }
    } else {
        if (h == 0) {
            HU u;
            u.u[0] = *(const unsigned*)(xr + 4 + 2 * e);    // pos.xy
            u.u[1] = *(const unsigned*)(xr + 34 + 2 * e);   // vel.xy
            bf = u.h;
        } else {
            bf[0] = xr[64 + e];              // k=4 scal
            bf[1] = (_Float16)1.f;           // k=5 bias
        }
    }
    const v16f d = MFMA32(A1, bf, z16);      // H^T (32ch x 32rows)
    const v4h p0 = pack4(fmaxf(d[0], 0.f), fmaxf(d[1], 0.f), fmaxf(d[2], 0.f), fmaxf(d[3], 0.f));
    const v4h p1 = pack4(fmaxf(d[4], 0.f), fmaxf(d[5], 0.f), fmaxf(d[6], 0.f), fmaxf(d[7], 0.f));
    const v4h p2 = pack4(fmaxf(d[8], 0.f), fmaxf(d[9], 0.f), fmaxf(d[10], 0.f), fmaxf(d[11], 0.f));
    const v4h p3 = pack4(fmaxf(d[12], 0.f), fmaxf(d[13], 0.f), fmaxf(d[14], 0.f), fmaxf(d[15], 0.f));
    v16f ca = MFMA32(A2[0], p0, z16);
    ca = MFMA32(A2[2], p2, ca);
    v16f cb = MFMA32(A2[1], p1, z16);
    cb = MFMA32(A2[3], p3, cb);
    float e2[8], part = 0.f;
    #pragma unroll
    for (int r = 0; r < 8; ++r) {
        e2[r] = fmaxf(ca[r] + cb[r] + b2v[r], 0.f);
        part += stl[r] * e2[r];
    }
    part += __shfl_xor(part, 32);
    const float p = __builtin_amdgcn_exp2f(part);
    l += p;
    #pragma unroll
    for (int r = 0; r < 8; ++r) o[r] += p * e2[r];
}

// normalize + LayerNorm(16) + affine + relu -> two packed B chunks
__device__ __forceinline__ void ln_fin(float l, const float (&o)[8],
                                       const float (&gv)[8], const float (&blv)[8],
                                       v4h& c0, v4h& c1) {
    const float rl = 1.f / l;
    float a[8], sum = 0.f;
    #pragma unroll
    for (int r = 0; r < 8; ++r) { a[r] = o[r] * rl; sum += a[r]; }
    sum += __shfl_xor(sum, 32);
    const float mu = sum * 0.0625f;
    float var = 0.f;
    #pragma unroll
    for (int r = 0; r < 8; ++r) { a[r] -= mu; var += a[r] * a[r]; }
    var += __shfl_xor(var, 32);
    const float inv = rsqrtf(var * 0.0625f + 1e-5f);
    float v[8];
    #pragma unroll
    for (int r = 0; r < 8; ++r) v[r] = fmaxf(a[r] * inv * gv[r] + blv[r], 0.f);
    c0 = pack4(v[0], v[1], v[2], v[3]);
    c1 = pack4(v[4], v[5], v[6], v[7]);
}

__global__ __launch_bounds__(256)
void actor_mfma(const float* __restrict__ x,
                const float* __restrict__ en_w1, const float* __restrict__ en_b1,
                const float* __restrict__ en_w2, const float* __restrict__ en_b2,
                const float* __restrict__ oa_w1, const float* __restrict__ oa_b1,
                const float* __restrict__ oa_w2, const float* __restrict__ oa_b2,
                const float* __restrict__ oa_g,  const float* __restrict__ oa_bln,
                const float* __restrict__ g_w1,  const float* __restrict__ g_b1,
                const float* __restrict__ g_w2,  const float* __restrict__ g_b2,
                const float* __restrict__ g_g,   const float* __restrict__ g_bln,
                const float* __restrict__ m_w1,  const float* __restrict__ m_b1,
                const float* __restrict__ m_w2,  const float* __restrict__ m_b2,
                const float* __restrict__ m_w3,  const float* __restrict__ m_b3,
                float* __restrict__ out, int B)
{
    const int lane = threadIdx.x & 63, wid = threadIdx.x >> 6;
    const int n = lane & 31, h = lane >> 5;

    __shared__ __align__(16) _Float16 xs_all[4][32 * XSS];
    _Float16* xs = xs_all[wid];

    const int r0 = blockIdx.x * 128 + wid * 32;
    const bool wvalid = (r0 < B);

    // ---- stage 32 rows as f16 (float4 loads, packed b64 LDS writes) ----
    if (wvalid) {
        const float* __restrict__ xp = x + (size_t)r0 * OBS;
        if (r0 + 32 <= B) {
            #pragma unroll
            for (int i = 0; i < 16; ++i) {
                const int gI = i * 64 + lane;
                if (gI < 992) {                  // 32 rows x 31 float4 (cols 0..123)
                    const int row = gI / 31;
                    const int c4 = gI - row * 31;
                    const f4u v = *(const f4u*)(xp + row * 127 + c4 * 4);
                    PK q;
                    q.p[0] = __builtin_amdgcn_cvt_pkrtz(v[0], v[1]);
                    q.p[1] = __builtin_amdgcn_cvt_pkrtz(v[2], v[3]);
                    *(uint2*)(xs + row * XSS + c4 * 4) = q.u;
                }
            }
            #pragma unroll
            for (int t = 0; t < 2; ++t) {        // tail cols 124..126
                const int idx = t * 64 + lane;
                if (idx < 96) {
                    const int row = idx / 3;
                    const int c = 124 + idx - row * 3;
                    xs[row * XSS + c] = (_Float16)xp[row * 127 + c];
                }
            }
        } else {
            const int lim = (B - r0) * OBS;
            for (int i = 0; i < 64; ++i) {
                const int f = i * 64 + lane;
                if (f < lim) {
                    const int r = f / 127;
                    xs[f + 5 * r] = (_Float16)xp[f];
                }
            }
        }
    }
    __syncthreads();

    // reg index -> channel: m = (r&3) + 8*(r>>2) + 4h  (r<8 covers 16 ch)
    v16f z16;
    #pragma unroll
    for (int r = 0; r < 16; ++r) z16[r] = 0.f;

    // ---- encoder weight fragments ----
    const v4h sA1 = a1frag(en_w1, en_b1, 4, n, h);
    v4h sA2[4], fA2[4], oA2[4];
    #pragma unroll
    for (int s = 0; s < 4; ++s) {
        sA2[s] = a2frag(en_w2, s, n, h);
        fA2[s] = a2frag(g_w2, s, n, h);
        oA2[s] = a2frag(oa_w2, s, n, h);
    }
    const v4h fA1 = a1frag(g_w1, g_b1, 3, n, h);
    const v4h oA1 = a1frag(oa_w1, oa_b1, 5, n, h);
    float sb2v[8], fb2v[8], ob2v[8];
    #pragma unroll
    for (int r = 0; r < 8; ++r) {
        const int m = (r & 3) + 8 * (r >> 2) + 4 * h;
        sb2v[r] = en_b2[m];
        fb2v[r] = g_b2[m];
        ob2v[r] = oa_b2[m];
    }

    // ---- self encoder (32 rows) ----
    const _Float16* xr = xs + n * XSS;
    float st[8], stl[8];
    v4h Bs0, Bs1;
    {
        v4h bs = zero4h();
        if (h == 0) bs = *(const v4h*)xr;        // x0..x3
        else        bs[0] = (_Float16)1.f;       // k=4 bias
        const v16f d = MFMA32(sA1, bs, z16);
        const v4h p0 = pack4(fmaxf(d[0], 0.f), fmaxf(d[1], 0.f), fmaxf(d[2], 0.f), fmaxf(d[3], 0.f));
        const v4h p1 = pack4(fmaxf(d[4], 0.f), fmaxf(d[5], 0.f), fmaxf(d[6], 0.f), fmaxf(d[7], 0.f));
        const v4h p2 = pack4(fmaxf(d[8], 0.f), fmaxf(d[9], 0.f), fmaxf(d[10], 0.f), fmaxf(d[11], 0.f));
        const v4h p3 = pack4(fmaxf(d[12], 0.f), fmaxf(d[13], 0.f), fmaxf(d[14], 0.f), fmaxf(d[15], 0.f));
        v16f ca = MFMA32(sA2[0], p0, z16);
        ca = MFMA32(sA2[2], p2, ca);
        v16f cb = MFMA32(sA2[1], p1, z16);
        cb = MFMA32(sA2[3], p3, cb);
        const float SK = 0.25f * 1.44269504088896f;   // (1/sqrt(16))*log2(e)
        #pragma unroll
        for (int r = 0; r < 8; ++r) {
            st[r] = fmaxf(ca[r] + cb[r] + sb2v[r], 0.f);
            stl[r] = st[r] * SK;
        }
        Bs0 = pack4(st[0], st[1], st[2], st[3]);
        Bs1 = pack4(st[4], st[5], st[6], st[7]);
    }

    // ---- fused entity loop: food(16) + other(15) ----
    float lf = 0.f, lo = 0.f;
    float of[8], oo[8];
    #pragma unroll
    for (int r = 0; r < 8; ++r) { of[r] = 0.f; oo[r] = 0.f; }
    #pragma unroll 2
    for (int e = 0; e < 16; ++e) {
        entity_step<1>(xr, e, h, fA1, fA2, fb2v, stl, lf, of, z16);
        if (e < 15)
            entity_step<0>(xr, e, h, oA1, oA2, ob2v, stl, lo, oo, z16);
    }

    // ---- finalize branches ----
    float fgv[8], fblv[8], ogv[8], oblv[8];
    #pragma unroll
    for (int r = 0; r < 8; ++r) {
        const int m = (r & 3) + 8 * (r >> 2) + 4 * h;
        fgv[r] = g_g[m];  fblv[r] = g_bln[m];
        ogv[r] = oa_g[m]; oblv[r] = oa_bln[m];
    }
    v4h Bf0, Bf1, Bo0, Bo1;
    ln_fin(lf, of, fgv, fblv, Bf0, Bf1);
    ln_fin(lo, oo, ogv, oblv, Bo0, Bo1);

    // ---- merge MLP: 48 -> 32 lrelu -> 32 lrelu -> 2 tanh ----
    v4h one_h0 = zero4h();
    if (h == 0) one_h0[0] = (_Float16)1.f;

    v16f m1 = MFMA32(wfrag(m_w1, 32, 48, 0, n, h, 32), Bs0, z16);
    m1 = MFMA32(wfrag(m_w1, 32, 48, 1, n, h, 32), Bs1, m1);
    m1 = MFMA32(wfrag(m_w1, 32, 48, 2, n, h, 32), Bf0, m1);
    m1 = MFMA32(wfrag(m_w1, 32, 48, 3, n, h, 32), Bf1, m1);
    m1 = MFMA32(wfrag(m_w1, 32, 48, 4, n, h, 32), Bo0, m1);
    m1 = MFMA32(wfrag(m_w1, 32, 48, 5, n, h, 32), Bo1, m1);
    m1 = MFMA32(bfragA(m_b1, n, h, 32), one_h0, m1);
    v4h q[4];
    #pragma unroll
    for (int s = 0; s < 4; ++s) {
        float t0 = m1[4 * s],     t1 = m1[4 * s + 1];
        float t2 = m1[4 * s + 2], t3 = m1[4 * s + 3];
        q[s] = pack4(fmaxf(t0, 0.01f * t0), fmaxf(t1, 0.01f * t1),
                     fmaxf(t2, 0.01f * t2), fmaxf(t3, 0.01f * t3));
    }
    v16f m2 = MFMA32(wfrag(m_w2, 32, 32, 0, n, h, 32), q[0], z16);
    m2 = MFMA32(wfrag(m_w2, 32, 32, 1, n, h, 32), q[1], m2);
    m2 = MFMA32(wfrag(m_w2, 32, 32, 2, n, h, 32), q[2], m2);
    m2 = MFMA32(wfrag(m_w2, 32, 32, 3, n, h, 32), q[3], m2);
    m2 = MFMA32(bfragA(m_b2, n, h, 32), one_h0, m2);
    v4h z[4];
    #pragma unroll
    for (int s = 0; s < 4; ++s) {
        float t0 = m2[4 * s],     t1 = m2[4 * s + 1];
        float t2 = m2[4 * s + 2], t3 = m2[4 * s + 3];
        z[s] = pack4(fmaxf(t0, 0.01f * t0), fmaxf(t1, 0.01f * t1),
                     fmaxf(t2, 0.01f * t2), fmaxf(t3, 0.01f * t3));
    }
    v16f m3 = MFMA32(wfrag(m_w3, 2, 32, 0, n, h, 2), z[0], z16);
    m3 = MFMA32(wfrag(m_w3, 2, 32, 1, n, h, 2), z[1], m3);
    m3 = MFMA32(wfrag(m_w3, 2, 32, 2, n, h, 2), z[2], m3);
    m3 = MFMA32(wfrag(m_w3, 2, 32, 3, n, h, 2), z[3], m3);
    m3 = MFMA32(bfragA(m_b3, n, h, 2), one_h0, m3);

    if (h == 0 && wvalid && r0 + n < B) {
        float2 res;
        res.x = fast_tanh(m3[0]);   // reg0 -> m=0
        res.y = fast_tanh(m3[1]);   // reg1 -> m=1
        *(float2*)(out + (size_t)(r0 + n) * 2) = res;
    }
}

extern "C" void kernel_launch(void* const* d_in, const int* in_sizes, int n_in,
                              void* d_out, int out_size, void* d_ws, size_t ws_size,
                              hipStream_t stream) {
    const int B = in_sizes[0] / OBS;
    const float* xin = (const float*)d_in[0];
    const float* en_w1 = (const float*)d_in[1];
    const float* en_b1 = (const float*)d_in[2];
    const float* en_w2 = (const float*)d_in[3];
    const float* en_b2 = (const float*)d_in[4];
    const float* oa_w1 = (const float*)d_in[5];
    const float* oa_b1 = (const float*)d_in[6];
    const float* oa_w2 = (const float*)d_in[7];
    const float* oa_b2 = (const float*)d_in[8];
    const float* oa_g  = (const float*)d_in[9];
    const float* oa_bl = (const float*)d_in[10];
    const float* g_w1  = (const float*)d_in[11];
    const float* g_b1  = (const float*)d_in[12];
    const float* g_w2  = (const float*)d_in[13];
    const float* g_b2  = (const float*)d_in[14];
    const float* g_g   = (const float*)d_in[15];
    const float* g_bl  = (const float*)d_in[16];
    const float* m_w1  = (const float*)d_in[17];
    const float* m_b1  = (const float*)d_in[18];
    const float* m_w2  = (const float*)d_in[19];
    const float* m_b2  = (const float*)d_in[20];
    const float* m_w3  = (const float*)d_in[21];
    const float* m_b3  = (const float*)d_in[22];

    const int rows_per_block = 128;  // 4 waves x 32 rows
    const int grid = (B + rows_per_block - 1) / rows_per_block;
    actor_mfma<<<grid, 256, 0, stream>>>(
        xin, en_w1, en_b1, en_w2, en_b2,
        oa_w1, oa_b1, oa_w2, oa_b2, oa_g, oa_bl,
        g_w1, g_b1, g_w2, g_b2, g_g, g_bl,
        m_w1, m_b1, m_w2, m_b2, m_w3, m_b3,
        (float*)d_out, B);
}

// Round 8
// 298.039 us; speedup vs baseline: 1.4927x; 1.0214x over previous
//
#include <hip/hip_runtime.h>
#include <math.h>

// Actor_att1 on gfx950 — R8: 32x32x16 (gfx950 2xK) retile.
// One wave = 32 rows. K=16 B layout: n=lane&31, k=8*(lane>>5)+j.
// D layout: m=(r&3)+8*(r>>2)+4h (m74/m101). D->B duality restored by
// permuting L1 output channels with bitswap23(m): D regs [0..7]=B chunk0,
// [8..15]=B chunk1. All consumers (L2, merge) index weights by
// ch(j,h)=(j&3)+8*(j>>2)+4h within each 16-ch chunk.
// Biases: L1 as constant-1 feature; L2/merge via epilogue or C-init.

#define OBS 127
#define XSS 132   // f16 LDS row stride (264B, 8B-aligned, 2-way-free banks)

typedef _Float16 v4h  __attribute__((ext_vector_type(4)));
typedef _Float16 v8h  __attribute__((ext_vector_type(8)));
typedef __fp16   p2h  __attribute__((ext_vector_type(2)));
typedef float    v16f __attribute__((ext_vector_type(16)));
typedef float    f4u  __attribute__((ext_vector_type(4), aligned(4)));

#define MFMA16(a, b, c) __builtin_amdgcn_mfma_f32_32x32x16_f16((a), (b), (c), 0, 0, 0)

union PK8 { p2h p[4]; v8h h; };
union HU8 { unsigned u[4]; v8h h; _Float16 e[8]; };

__device__ __forceinline__ v8h zero8h() {
    v8h z;
    #pragma unroll
    for (int j = 0; j < 8; ++j) z[j] = (_Float16)0.f;
    return z;
}
// pack 8 fp32 (v16f slice) -> v8h, RTZ
__device__ __forceinline__ v8h pk8(const v16f& d, int b) {
    PK8 q;
    q.p[0] = __builtin_amdgcn_cvt_pkrtz(d[b],     d[b + 1]);
    q.p[1] = __builtin_amdgcn_cvt_pkrtz(d[b + 2], d[b + 3]);
    q.p[2] = __builtin_amdgcn_cvt_pkrtz(d[b + 4], d[b + 5]);
    q.p[3] = __builtin_amdgcn_cvt_pkrtz(d[b + 6], d[b + 7]);
    return q.h;
}
// pack + relu (relu after cvt == cvt after relu; pk_max is 2x cheaper)
__device__ __forceinline__ v8h pkr8(const v16f& d, int b) {
    return __builtin_elementwise_max(pk8(d, b), zero8h());
}
__device__ __forceinline__ v8h pk8f(const float (&v)[8]) {
    PK8 q;
    q.p[0] = __builtin_amdgcn_cvt_pkrtz(v[0], v[1]);
    q.p[1] = __builtin_amdgcn_cvt_pkrtz(v[2], v[3]);
    q.p[2] = __builtin_amdgcn_cvt_pkrtz(v[4], v[5]);
    q.p[3] = __builtin_amdgcn_cvt_pkrtz(v[6], v[7]);
    return q.h;
}
__device__ __forceinline__ v8h lrelu8(v8h t) {   // max(x, 0.01x) in packed f16
    const v8h s = t * (_Float16)0.01f;
    return __builtin_elementwise_max(t, s);
}
// L1 A-frag: output ch permuted by bitswap23; bias row at k==kin.
__device__ __forceinline__ v8h a1fragK16(const float* __restrict__ W,
                                         const float* __restrict__ b,
                                         int kin, int m, int h) {
    const int Lm = (m & ~12) | ((m & 4) << 1) | ((m & 8) >> 1);
    v8h r;
    #pragma unroll
    for (int j = 0; j < 8; ++j) {
        const int k = 8 * h + j;
        const float v = (k < kin) ? W[k * 32 + Lm] : (k == kin ? b[Lm] : 0.f);
        r[j] = (_Float16)v;
    }
    return r;
}
// L2 A chunk s: pairs with B logical ch 16s+8h+j (W2 is 32x16).
__device__ __forceinline__ v8h a2fragK16(const float* __restrict__ W2,
                                         int s, int m, int h) {
    v8h r;
    #pragma unroll
    for (int j = 0; j < 8; ++j)
        r[j] = (_Float16)((m < 16) ? W2[(16 * s + 8 * h + j) * 16 + m] : 0.f);
    return r;
}
// merge A chunk: B position (h,j) holds source ch base+(j&3)+8*(j>>2)+4h.
__device__ __forceinline__ v8h mfragK16(const float* __restrict__ W, int ncols,
                                        int base, int m, int h, int colmax) {
    v8h r;
    #pragma unroll
    for (int j = 0; j < 8; ++j) {
        const int ch = base + (j & 3) + 8 * (j >> 2) + 4 * h;
        r[j] = (_Float16)((m < colmax) ? W[ch * ncols + m] : 0.f);
    }
    return r;
}
__device__ __forceinline__ float fast_tanh(float x) {
    x = fminf(fmaxf(x, -15.f), 15.f);
    const float ex = __expf(2.f * x);
    return (ex - 1.f) / (ex + 1.f);
}

// One entity: L1 (1 MFMA) -> relu-pack -> L2 (2 chained MFMA) -> softmax acc.
template <int BR>
__device__ __forceinline__ void entity_step(const _Float16* __restrict__ xr,
                                            int e, int h,
                                            v8h A1, v8h A2a, v8h A2b,
                                            const float (&b2v)[8],
                                            const float (&stl)[8],
                                            float& l, float (&o)[8],
                                            v16f z16) {
    v8h bf = zero8h();
    if (h == 0) {
        HU8 u;
        #pragma unroll
        for (int j = 0; j < 4; ++j) u.u[j] = 0;
        if (BR == 1) {
            u.e[0] = xr[79 + 3 * e];
            u.e[1] = xr[80 + 3 * e];
            u.e[2] = xr[81 + 3 * e];
            u.e[3] = (_Float16)1.f;          // k=3 bias feature
        } else {
            u.u[0] = *(const unsigned*)(xr + 4 + 2 * e);    // pos.xy
            u.u[1] = *(const unsigned*)(xr + 34 + 2 * e);   // vel.xy
            u.e[4] = xr[64 + e];             // k=4 scal
            u.e[5] = (_Float16)1.f;          // k=5 bias
        }
        bf = u.h;
    }
    const v16f dH = MFMA16(A1, bf, z16);     // H^T, channel-permuted
    const v8h p0 = pkr8(dH, 0);              // B chunk0 (logical ch 0..15)
    const v8h p1 = pkr8(dH, 8);              // B chunk1 (logical ch 16..31)
    v16f c = MFMA16(A2a, p0, z16);
    c = MFMA16(A2b, p1, c);
    float e2[8], part = 0.f;
    #pragma unroll
    for (int r = 0; r < 8; ++r) {
        e2[r] = fmaxf(c[r] + b2v[r], 0.f);
        part += stl[r] * e2[r];
    }
    part += __shfl_xor(part, 32);
    const float p = __builtin_amdgcn_exp2f(part);
    l += p;
    #pragma unroll
    for (int r = 0; r < 8; ++r) o[r] += p * e2[r];
}

// normalize + LayerNorm(16) + affine + relu -> packed merge B chunk
__device__ __forceinline__ v8h ln_fin(float l, const float (&o)[8],
                                      const float (&gv)[8], const float (&blv)[8]) {
    const float rl = 1.f / l;
    float a[8], sum = 0.f;
    #pragma unroll
    for (int r = 0; r < 8; ++r) { a[r] = o[r] * rl; sum += a[r]; }
    sum += __shfl_xor(sum, 32);
    const float mu = sum * 0.0625f;
    float var = 0.f;
    #pragma unroll
    for (int r = 0; r < 8; ++r) { a[r] -= mu; var += a[r] * a[r]; }
    var += __shfl_xor(var, 32);
    const float inv = rsqrtf(var * 0.0625f + 1e-5f);
    float v[8];
    #pragma unroll
    for (int r = 0; r < 8; ++r) v[r] = fmaxf(a[r] * inv * gv[r] + blv[r], 0.f);
    return pk8f(v);
}

__global__ __launch_bounds__(256)
void actor_mfma(const float* __restrict__ x,
                const float* __restrict__ en_w1, const float* __restrict__ en_b1,
                const float* __restrict__ en_w2, const float* __restrict__ en_b2,
                const float* __restrict__ oa_w1, const float* __restrict__ oa_b1,
                const float* __restrict__ oa_w2, const float* __restrict__ oa_b2,
                const float* __restrict__ oa_g,  const float* __restrict__ oa_bln,
                const float* __restrict__ g_w1,  const float* __restrict__ g_b1,
                const float* __restrict__ g_w2,  const float* __restrict__ g_b2,
                const float* __restrict__ g_g,   const float* __restrict__ g_bln,
                const float* __restrict__ m_w1,  const float* __restrict__ m_b1,
                const float* __restrict__ m_w2,  const float* __restrict__ m_b2,
                const float* __restrict__ m_w3,  const float* __restrict__ m_b3,
                float* __restrict__ out, int B)
{
    const int lane = threadIdx.x & 63, wid = threadIdx.x >> 6;
    const int n = lane & 31, h = lane >> 5;

    __shared__ __align__(16) _Float16 xs_all[4][32 * XSS];
    _Float16* xs = xs_all[wid];

    const int r0 = blockIdx.x * 128 + wid * 32;
    const bool wvalid = (r0 < B);

    // ---- stage 32 rows as f16 ----
    if (wvalid) {
        const float* __restrict__ xp = x + (size_t)r0 * OBS;
        if (r0 + 32 <= B) {
            #pragma unroll
            for (int i = 0; i < 16; ++i) {
                const int gI = i * 64 + lane;
                if (gI < 992) {                  // 32 rows x 31 float4
                    const int row = gI / 31;
                    const int c4 = gI - row * 31;
                    const f4u v = *(const f4u*)(xp + row * 127 + c4 * 4);
                    PK8 q;
                    q.p[0] = __builtin_amdgcn_cvt_pkrtz(v[0], v[1]);
                    q.p[1] = __builtin_amdgcn_cvt_pkrtz(v[2], v[3]);
                    *(uint2*)(xs + row * XSS + c4 * 4) = *(const uint2*)&q;
                }
            }
            #pragma unroll
            for (int t = 0; t < 2; ++t) {        // tail cols 124..126
                const int idx = t * 64 + lane;
                if (idx < 96) {
                    const int row = idx / 3;
                    const int c = 124 + idx - row * 3;
                    xs[row * XSS + c] = (_Float16)xp[row * 127 + c];
                }
            }
        } else {
            const int lim = (B - r0) * OBS;
            for (int i = 0; i < 64; ++i) {
                const int f = i * 64 + lane;
                if (f < lim) {
                    const int r = f / 127;
                    xs[f + 5 * r] = (_Float16)xp[f];
                }
            }
        }
    }
    __syncthreads();

    v16f z16;
    #pragma unroll
    for (int r = 0; r < 16; ++r) z16[r] = 0.f;

    // per-lane D channel m(r,h) for r<8
    float sb2v[8], fb2v[8], ob2v[8];
    #pragma unroll
    for (int r = 0; r < 8; ++r) {
        const int m = (r & 3) + 8 * (r >> 2) + 4 * h;
        sb2v[r] = en_b2[m];
        fb2v[r] = g_b2[m];
        ob2v[r] = oa_b2[m];
    }

    const _Float16* xr = xs + n * XSS;
    float st[8], stl[8];
    v8h Bs;
    {   // ---- self encoder ----
        const v8h sA1 = a1fragK16(en_w1, en_b1, 4, n, h);
        const v8h sA2a = a2fragK16(en_w2, 0, n, h);
        const v8h sA2b = a2fragK16(en_w2, 1, n, h);
        v8h bs = zero8h();
        if (h == 0) {
            HU8 u;
            #pragma unroll
            for (int j = 0; j < 4; ++j) u.u[j] = 0;
            *(uint2*)&u.u[0] = *(const uint2*)xr;   // x0..x3 (8B aligned)
            u.e[4] = (_Float16)1.f;                 // k=4 bias
            bs = u.h;
        }
        const v16f dS = MFMA16(sA1, bs, z16);
        v16f cS = MFMA16(sA2a, pkr8(dS, 0), z16);
        cS = MFMA16(sA2b, pkr8(dS, 8), cS);
        const float SK = 0.25f * 1.44269504088896f;   // (1/4)*log2(e)
        float sv[8];
        #pragma unroll
        for (int r = 0; r < 8; ++r) {
            sv[r] = fmaxf(cS[r] + sb2v[r], 0.f);
            st[r] = sv[r];
            stl[r] = sv[r] * SK;
        }
        Bs = pk8f(sv);
    }

    // ---- fused entity loop ----
    const v8h fA1 = a1fragK16(g_w1, g_b1, 3, n, h);
    const v8h fA2a = a2fragK16(g_w2, 0, n, h);
    const v8h fA2b = a2fragK16(g_w2, 1, n, h);
    const v8h oA1 = a1fragK16(oa_w1, oa_b1, 5, n, h);
    const v8h oA2a = a2fragK16(oa_w2, 0, n, h);
    const v8h oA2b = a2fragK16(oa_w2, 1, n, h);

    float lf = 0.f, lo = 0.f, of[8], oo[8];
    #pragma unroll
    for (int r = 0; r < 8; ++r) { of[r] = 0.f; oo[r] = 0.f; }
    #pragma unroll 2
    for (int e = 0; e < 16; ++e) {
        entity_step<1>(xr, e, h, fA1, fA2a, fA2b, fb2v, stl, lf, of, z16);
        if (e < 15)
            entity_step<0>(xr, e, h, oA1, oA2a, oA2b, ob2v, stl, lo, oo, z16);
    }

    // ---- finalize branches ----
    float fgv[8], fblv[8], ogv[8], oblv[8];
    #pragma unroll
    for (int r = 0; r < 8; ++r) {
        const int m = (r & 3) + 8 * (r >> 2) + 4 * h;
        fgv[r] = g_g[m];  fblv[r] = g_bln[m];
        ogv[r] = oa_g[m]; oblv[r] = oa_bln[m];
    }
    const v8h Bf = ln_fin(lf, of, fgv, fblv);
    const v8h Bo = ln_fin(lo, oo, ogv, oblv);

    // ---- merge MLP: 48 -> 32 lrelu -> 32 lrelu -> 2 tanh ----
    v16f m1C, m2C;
    #pragma unroll
    for (int r = 0; r < 16; ++r) {
        const int m = (r & 3) + 8 * (r >> 2) + 4 * h;
        m1C[r] = m_b1[m];
        m2C[r] = m_b2[m];
    }
    v16f m1 = MFMA16(mfragK16(m_w1, 32, 0, n, h, 32), Bs, m1C);
    m1 = MFMA16(mfragK16(m_w1, 32, 16, n, h, 32), Bf, m1);
    m1 = MFMA16(mfragK16(m_w1, 32, 32, n, h, 32), Bo, m1);
    const v8h q0 = lrelu8(pk8(m1, 0));
    const v8h q1 = lrelu8(pk8(m1, 8));
    v16f m2 = MFMA16(mfragK16(m_w2, 32, 0, n, h, 32), q0, m2C);
    m2 = MFMA16(mfragK16(m_w2, 32, 16, n, h, 32), q1, m2);
    const v8h z0 = lrelu8(pk8(m2, 0));
    const v8h z1 = lrelu8(pk8(m2, 8));
    v16f m3 = MFMA16(mfragK16(m_w3, 2, 0, n, h, 2), z0, z16);
    m3 = MFMA16(mfragK16(m_w3, 2, 16, n, h, 2), z1, m3);

    if (h == 0 && wvalid && r0 + n < B) {
        float2 res;
        res.x = fast_tanh(m3[0] + m_b3[0]);   // reg0 -> m=0
        res.y = fast_tanh(m3[1] + m_b3[1]);   // reg1 -> m=1
        *(float2*)(out + (size_t)(r0 + n) * 2) = res;
    }
}

extern "C" void kernel_launch(void* const* d_in, const int* in_sizes, int n_in,
                              void* d_out, int out_size, void* d_ws, size_t ws_size,
                              hipStream_t stream) {
    const int B = in_sizes[0] / OBS;
    const float* xin = (const float*)d_in[0];
    const float* en_w1 = (const float*)d_in[1];
    const float* en_b1 = (const float*)d_in[2];
    const float* en_w2 = (const float*)d_in[3];
    const float* en_b2 = (const float*)d_in[4];
    const float* oa_w1 = (const float*)d_in[5];
    const float* oa_b1 = (const float*)d_in[6];
    const float* oa_w2 = (const float*)d_in[7];
    const float* oa_b2 = (const float*)d_in[8];
    const float* oa_g  = (const float*)d_in[9];
    const float* oa_bl = (const float*)d_in[10];
    const float* g_w1  = (const float*)d_in[11];
    const float* g_b1  = (const float*)d_in[12];
    const float* g_w2  = (const float*)d_in[13];
    const float* g_b2  = (const float*)d_in[14];
    const float* g_g   = (const float*)d_in[15];
    const float* g_bl  = (const float*)d_in[16];
    const float* m_w1  = (const float*)d_in[17];
    const float* m_b1  = (const float*)d_in[18];
    const float* m_w2  = (const float*)d_in[19];
    const float* m_b2  = (const float*)d_in[20];
    const float* m_w3  = (const float*)d_in[21];
    const float* m_b3  = (const float*)d_in[22];

    const int rows_per_block = 128;  // 4 waves x 32 rows
    const int grid = (B + rows_per_block - 1) / rows_per_block;
    actor_mfma<<<grid, 256, 0, stream>>>(
        xin, en_w1, en_b1, en_w2, en_b2,
        oa_w1, oa_b1, oa_w2, oa_b2, oa_g, oa_bl,
        g_w1, g_b1, g_w2, g_b2, g_g, g_bl,
        m_w1, m_b1, m_w2, m_b2, m_w3, m_b3,
        (float*)d_out, B);
}